// Round 3
// baseline (451.144 us; speedup 1.0000x reference)
//
#include <hip/hip_runtime.h>

// Problem shape (fixed by setup_inputs): left/right [B,C,H,W] fp32,
// out volume [B,C,D,H,W] fp32:
//   out[b,c,d,y,x] = left[b,c,y,x] - right[b,c,y,x-d]  (x>=d, else 0)
#define BB 2
#define CC 32
#define HH 96
#define WW 320
#define DD 48
#define NBC   (BB * CC)              // 64 fused b*C+c slices
#define ROWSZ WW                     // 320 floats per row
#define TOT4  (BB*CC*DD*HH*WW/4)     // 23,592,960 float4 outputs
#define NBLK  2048                   // 8 blocks/CU exactly -> all resident
#define NTHR  256                    // 4 waves/block, 32 waves/CU
#define SWEEP (NBLK * NTHR)          // 524,288 float4 per sweep (8 MB front)
#define NSW   (TOT4 / SWEEP)         // 45 sweeps exactly, no tail

// Flat grid-stride kernel that covers the 377 MB output in PURE ADDRESS
// ORDER, mimicking __amd_rocclr_fillBufferAligned (measured 6.2 TB/s on
// this very buffer at 256-thr blocks). Evidence from two prior variants:
//  - row-kernel (48 stores 120 KB apart per thread): ~145 us
//  - per-(bc,d) contiguous 120 KB slices (1536 independent streams): ~170 us
// Both >> the 63 us write roofline -> DRAM wants ONE coherent moving
// write front, not per-block contiguity. Here the whole GPU advances a
// single ~8 MB window per sweep, 45 sweeps.
//
// Reads: left+right total 15.7 MB -> L2/L3-resident after sweep 0; the
// 48x re-read is cache bandwidth (~755 MB @ 34.5 TB/s ~ 22 us,
// overlapped), not HBM. Index decomposition n -> (bc,d,y,x) uses
// constant divisors (compiler emits magic multiplies).
__global__ __launch_bounds__(NTHR) void diffvol_kernel(
        const float* __restrict__ left,
        const float* __restrict__ right,
        float* __restrict__ out) {
    const unsigned gtid = blockIdx.x * NTHR + threadIdx.x;   // 0..524287

    #pragma unroll 1
    for (int s = 0; s < NSW; ++s) {
        const unsigned n   = (unsigned)s * SWEEP + gtid;     // float4 index
        const unsigned x4  = n % 80;                         // float4 column
        const unsigned row = n / 80;                         // (bc*48+d)*96+y
        const unsigned bc  = row / (DD * HH);                // /4608
        const unsigned r1  = row - bc * (DD * HH);
        const unsigned d   = r1 / HH;                        // /96
        const unsigned y   = r1 - d * HH;
        const unsigned x0  = x4 * 4;

        const float* lrow = left  + (bc * HH + y) * ROWSZ;
        const float* rrow = right + (bc * HH + y) * ROWSZ;

        const float4 l4 = *reinterpret_cast<const float4*>(lrow + x0);
        const int sb = (int)x0 - (int)d;                     // source col of k=0
        float4 v;
        if (sb >= 0) {
            // Common case (>=68/80 columns): all four sources in-range.
            const float* rp = rrow + sb;
            v.x = l4.x - rp[0];
            v.y = l4.y - rp[1];
            v.z = l4.z - rp[2];
            v.w = l4.w - rp[3];
        } else {
            // Left boundary: per-element validity, clamped gather.
            const float lv[4] = {l4.x, l4.y, l4.z, l4.w};
            float t[4];
            #pragma unroll
            for (int k = 0; k < 4; ++k) {
                const int src = sb + k;
                const float rv = rrow[src >= 0 ? src : 0];
                t[k] = (src >= 0) ? lv[k] - rv : 0.0f;
            }
            v = make_float4(t[0], t[1], t[2], t[3]);
        }
        reinterpret_cast<float4*>(out)[n] = v;               // pure sequential
    }
}

extern "C" void kernel_launch(void* const* d_in, const int* in_sizes, int n_in,
                              void* d_out, int out_size, void* d_ws, size_t ws_size,
                              hipStream_t stream) {
    const float* left  = (const float*)d_in[0];
    const float* right = (const float*)d_in[1];
    float* out = (float*)d_out;

    diffvol_kernel<<<NBLK, NTHR, 0, stream>>>(left, right, out);
}

// Round 4
// 377.745 us; speedup vs baseline: 1.1943x; 1.1943x over previous
//
#include <hip/hip_runtime.h>

// out[b,c,d,y,x] = left[b,c,y,x] - right[b,c,y,x-d]  (x>=d, else 0)
// left/right [B,C,H,W] fp32, out [B,C,D,H,W] fp32.
#define BB 2
#define CC 32
#define HH 96
#define WW 320
#define DD 48
#define NBC    (BB*CC)        // 64 fused b*C+c slices
#define W4     (WW/4)         // 80 float4 columns per row
#define SLICE4 (HH*W4)        // 7680 float4 per (bc,d) slice
// Main region: float4-cols 16..79 (x0 in [64,316]) -> x0-d >= 17 always
// valid, no predicates. 64 bc x 24 groups of 4 rows = 1536 blocks.
#define MAIN_BLKS (NBC*24)
// Left region: float4-cols 0..15 (x0 in [0,60]) -> per-element validity.
// 64 bc x 6 groups of 16 rows = 384 blocks.
#define LEFT_BLKS (NBC*6)

__device__ __forceinline__ float4 f4sub(float4 a, float4 b) {
    return make_float4(a.x-b.x, a.y-b.y, a.z-b.z, a.w-b.w);
}

// Lessons from rounds 0-3 (fill floor ~244 us is fixed; kernel deltas):
//   row-kernel scalar stores: +145us | per-(bc,d) slices: +170 | flat sweep: +210
// -> write-address locality is NOT the limit; per-output instruction count
//    and store width are. This kernel keeps the read-once LDS structure but
//    stores dwordx4 (1KB/wave-instr, 4x fewer store instrs, = fill's width)
// Sliding-quad trick: window [x0-d, x0-d+3] has wave-uniform, compile-time
// alignment per d. One aligned ds_read_b128 serves FOUR consecutive d's;
// shifted float4 assembled from two live quads with compile-time selects.
// 13 LDS reads + 48 {4 v_sub + 1 store} per thread = ~1.6 instr/element.
__global__ __launch_bounds__(256) void diffvol_kernel(
        const float* __restrict__ left,
        const float* __restrict__ right,
        float* __restrict__ out) {
    const int bid = blockIdx.x;
    const int tid = threadIdx.x;

    if (bid < MAIN_BLKS) {
        __shared__ float4 rrow[4*W4];           // 4 rows x 80 float4 = 5 KB
        const int bc = bid / 24;
        const int y0 = (bid % 24) * 4;
        const int r  = tid >> 6;                // 0..3 row
        const int c4 = 16 + (tid & 63);         // 16..79 float4 col

        // Stage 4 full right rows (320 float4) with 256 threads.
        const float4* rin = (const float4*)right + (size_t)(bc*HH + y0) * W4;
        rrow[tid] = rin[tid];
        if (tid < 4*W4 - 256) rrow[256 + tid] = rin[256 + tid];
        __syncthreads();

        const float4 l4 =
            ((const float4*)left)[(size_t)(bc*HH + y0 + r) * W4 + c4];
        float4* o4 = (float4*)out
                   + ((size_t)(bc*DD)*HH + (y0 + r)) * W4 + c4;
        const float4* lds = &rrow[r * W4];

        float4 pm1 = lds[c4];                   // P(0): cols [x0 .. x0+3]
        o4[0] = f4sub(l4, pm1);                 // d = 0
        #pragma unroll
        for (int m = 1; m <= 12; ++m) {
            const float4 pm = lds[c4 - m];      // P(m): cols [x0-4m .. x0-4m+3]
            // d = 4m-3..4m; window = floats [a..a+3] of concat(pm, pm1), a=4m-d
            o4[(size_t)(4*m-3)*SLICE4] = f4sub(l4, make_float4(pm.w, pm1.x, pm1.y, pm1.z));
            o4[(size_t)(4*m-2)*SLICE4] = f4sub(l4, make_float4(pm.z, pm.w, pm1.x, pm1.y));
            o4[(size_t)(4*m-1)*SLICE4] = f4sub(l4, make_float4(pm.y, pm.z, pm.w, pm1.x));
            if (m < 12)                          // d=48 doesn't exist
                o4[(size_t)(4*m)*SLICE4] = f4sub(l4, pm);
            pm1 = pm;
        }
    } else {
        __shared__ float4 rq[16*16];            // 16 rows x cols 0..63 = 4 KB
        const int lb = bid - MAIN_BLKS;
        const int bc = lb / 6;
        const int y0 = (lb % 6) * 16;
        const int ry = tid >> 4;                // 0..15 row
        const int c4 = tid & 15;                // 0..15 float4 col
        const int x0 = c4 * 4;

        rq[tid] = ((const float4*)right)[(size_t)(bc*HH + y0 + ry) * W4 + c4];
        __syncthreads();

        const float4 l4 =
            ((const float4*)left)[(size_t)(bc*HH + y0 + ry) * W4 + c4];
        float4* o4 = (float4*)out
                   + ((size_t)(bc*DD)*HH + (y0 + ry)) * W4 + c4;
        const float4* lds = &rq[ry * 16];

        float4 pm1 = lds[c4];
        o4[0] = f4sub(l4, pm1);                 // d = 0 always valid (x0>=0)
        #pragma unroll
        for (int m = 1; m <= 12; ++m) {
            // Clamp LDS index; garbage lanes are masked below (finite data).
            const float4 pm = lds[c4 >= m ? c4 - m : 0];
            #pragma unroll
            for (int a = 3; a >= 0; --a) {
                const int d = 4*m - a;
                if (d > 47) continue;
                float4 w;
                if      (a == 3) w = make_float4(pm.w, pm1.x, pm1.y, pm1.z);
                else if (a == 2) w = make_float4(pm.z, pm.w, pm1.x, pm1.y);
                else if (a == 1) w = make_float4(pm.y, pm.z, pm.w, pm1.x);
                else             w = pm;
                float4 v;
                v.x = (x0 + 0 >= d) ? l4.x - w.x : 0.0f;
                v.y = (x0 + 1 >= d) ? l4.y - w.y : 0.0f;
                v.z = (x0 + 2 >= d) ? l4.z - w.z : 0.0f;
                v.w = (x0 + 3 >= d) ? l4.w - w.w : 0.0f;
                o4[(size_t)d * SLICE4] = v;
            }
            pm1 = pm;
        }
    }
}

extern "C" void kernel_launch(void* const* d_in, const int* in_sizes, int n_in,
                              void* d_out, int out_size, void* d_ws, size_t ws_size,
                              hipStream_t stream) {
    const float* left  = (const float*)d_in[0];
    const float* right = (const float*)d_in[1];
    float* out = (float*)d_out;

    const int grid = MAIN_BLKS + LEFT_BLKS;     // 1920 blocks, 256 thr
    diffvol_kernel<<<grid, 256, 0, stream>>>(left, right, out);
}